// Round 1
// baseline (190.282 us; speedup 1.0000x reference)
//
#include <hip/hip_runtime.h>

// B=64, L=512, D=768, V=100
// summed[b,l,:] = w0 * pooler[b,l,:] + w1 * xt[b,:]
//   xt[b,d] = e0*W[0,d] + e1*W[1,d] + b_dense[d],  (e0,e1) = emb_table[ids[b]]
//   s00 = t0.t0, s01 = t0.t1, s11 = t1.t1
//   row0 softmax over (s00,s01), row1 softmax over (s01,s11); w = column sums
// LayerNorm closed form from (S0,S1,s00,s01,s11).

constexpr int Bc = 64;
constexpr int Lc = 512;
constexpr int Dc = 768;            // = 192 float4 = 3 float4 per lane (wave64)
constexpr float LN_EPS = 1e-6f;

__global__ __launch_bounds__(64) void hier_attn_ln_kernel(
    const int*   __restrict__ ids,        // (B,1)
    const float* __restrict__ pooler,     // (B,L,D)
    const float* __restrict__ emb_table,  // (V,2)
    const float* __restrict__ W,          // (2,D)
    const float* __restrict__ bvec,       // (D,)
    const float* __restrict__ gamma,      // (D,)
    const float* __restrict__ beta,       // (D,)
    float*       __restrict__ out)        // (B,L,D)
{
    const int row  = blockIdx.x;          // b*L + l
    const int b    = row >> 9;            // L = 512
    const int lane = threadIdx.x;

    const float4* prow4 = (const float4*)(pooler + (size_t)row * Dc);
    float4*       orow4 = (float4*)(out + (size_t)row * Dc);
    const float4* W0_4  = (const float4*)W;
    const float4* W1_4  = (const float4*)(W + Dc);
    const float4* b_4   = (const float4*)bvec;
    const float4* g_4   = (const float4*)gamma;
    const float4* be_4  = (const float4*)beta;

    const int id = ids[b];
    const float e0 = emb_table[id * 2 + 0];
    const float e1 = emb_table[id * 2 + 1];

    float4 t0[3], t1[3];
    float s00 = 0.f, s01 = 0.f, s11 = 0.f, S0 = 0.f, S1 = 0.f;

#pragma unroll
    for (int j = 0; j < 3; ++j) {
        const int idx4 = lane + j * 64;   // coalesced across wave
        float4 p  = prow4[idx4];
        float4 w0 = W0_4[idx4];
        float4 w1 = W1_4[idx4];
        float4 bd = b_4[idx4];
        float4 x;
        x.x = fmaf(e0, w0.x, fmaf(e1, w1.x, bd.x));
        x.y = fmaf(e0, w0.y, fmaf(e1, w1.y, bd.y));
        x.z = fmaf(e0, w0.z, fmaf(e1, w1.z, bd.z));
        x.w = fmaf(e0, w0.w, fmaf(e1, w1.w, bd.w));
        t0[j] = p;
        t1[j] = x;
        s00 += p.x*p.x + p.y*p.y + p.z*p.z + p.w*p.w;
        s01 += p.x*x.x + p.y*x.y + p.z*x.z + p.w*x.w;
        s11 += x.x*x.x + x.y*x.y + x.z*x.z + x.w*x.w;
        S0  += p.x + p.y + p.z + p.w;
        S1  += x.x + x.y + x.z + x.w;
    }

    // Full-wave butterfly reduction: every lane ends with the total.
#pragma unroll
    for (int off = 32; off > 0; off >>= 1) {
        s00 += __shfl_xor(s00, off);
        s01 += __shfl_xor(s01, off);
        s11 += __shfl_xor(s11, off);
        S0  += __shfl_xor(S0,  off);
        S1  += __shfl_xor(S1,  off);
    }

    // Two 2-way softmaxes (max-subtracted: s00 ~ O(768), naive exp overflows).
    const float m0  = fmaxf(s00, s01);
    const float a00 = __expf(s00 - m0);
    const float a01 = __expf(s01 - m0);
    const float r0  = 1.f / (a00 + a01);
    const float m1  = fmaxf(s01, s11);
    const float a10 = __expf(s01 - m1);
    const float a11 = __expf(s11 - m1);
    const float r1  = 1.f / (a10 + a11);
    const float w0s = a00 * r0 + a10 * r1;   // weight on t0
    const float w1s = a01 * r0 + a11 * r1;   // weight on t1

    const float invD = 1.f / (float)Dc;
    const float mean = (w0s * S0 + w1s * S1) * invD;
    const float ex2  = (w0s*w0s*s00 + 2.f*w0s*w1s*s01 + w1s*w1s*s11) * invD;
    const float var  = ex2 - mean * mean;
    const float rstd = rsqrtf(var + LN_EPS);

#pragma unroll
    for (int j = 0; j < 3; ++j) {
        const int idx4 = lane + j * 64;
        float4 gm = g_4[idx4];
        float4 bt = be_4[idx4];
        float4 o;
        o.x = (fmaf(w0s, t0[j].x, w1s * t1[j].x) - mean) * rstd * gm.x + bt.x;
        o.y = (fmaf(w0s, t0[j].y, w1s * t1[j].y) - mean) * rstd * gm.y + bt.y;
        o.z = (fmaf(w0s, t0[j].z, w1s * t1[j].z) - mean) * rstd * gm.z + bt.z;
        o.w = (fmaf(w0s, t0[j].w, w1s * t1[j].w) - mean) * rstd * gm.w + bt.w;
        orow4[idx4] = o;
    }
}

extern "C" void kernel_launch(void* const* d_in, const int* in_sizes, int n_in,
                              void* d_out, int out_size, void* d_ws, size_t ws_size,
                              hipStream_t stream) {
    const int*   ids       = (const int*)  d_in[0];
    const float* pooler    = (const float*)d_in[1];
    const float* emb_table = (const float*)d_in[2];
    const float* W_dense   = (const float*)d_in[3];
    const float* b_dense   = (const float*)d_in[4];
    const float* gamma     = (const float*)d_in[5];
    const float* beta      = (const float*)d_in[6];
    float* out = (float*)d_out;

    const int nrows = Bc * Lc;  // 32768
    hipLaunchKernelGGL(hier_attn_ln_kernel, dim3(nrows), dim3(64), 0, stream,
                       ids, pooler, emb_table, W_dense, b_dense, gamma, beta, out);
}

// Round 3
// 187.205 us; speedup vs baseline: 1.0164x; 1.0164x over previous
//
#include <hip/hip_runtime.h>

// B=64, L=512, D=768, V=100
// summed[b,l,:] = w0 * pooler[b,l,:] + w1 * xt[b,:]
//   xt[b,d] = e0*W[0,d] + e1*W[1,d] + b_dense[d],  (e0,e1) = emb_table[ids[b]]
//   s00 = t0.t0, s01 = t0.t1, s11 = t1.t1
//   row0 softmax over (s00,s01), row1 softmax over (s01,s11); w = column sums
// LayerNorm closed form from (S0,S1,s00,s01,s11).
//
// R1: 256-thread blocks (4 waves, one row per wave) — 64-thread blocks were
// workgroup-slot limited (~16 wg/CU -> 68% occupancy, 2.5 TB/s). 4 waves/block
// x 8 blocks/CU = 32 waves/CU. NT stores for out (write-once stream).
// R2: NT store must go through a native clang vector type, not float4
// (HIP_vector_type) — compile fix only.

constexpr int Bc = 64;
constexpr int Lc = 512;
constexpr int Dc = 768;            // = 192 float4 = 3 float4 per lane (wave64)
constexpr float LN_EPS = 1e-6f;
constexpr int WAVES_PER_BLOCK = 4;

typedef float nv_float4 __attribute__((ext_vector_type(4)));

__global__ __launch_bounds__(64 * WAVES_PER_BLOCK) void hier_attn_ln_kernel(
    const int*   __restrict__ ids,        // (B,1)
    const float* __restrict__ pooler,     // (B,L,D)
    const float* __restrict__ emb_table,  // (V,2)
    const float* __restrict__ W,          // (2,D)
    const float* __restrict__ bvec,       // (D,)
    const float* __restrict__ gamma,      // (D,)
    const float* __restrict__ beta,       // (D,)
    float*       __restrict__ out)        // (B,L,D)
{
    const int wave = threadIdx.x >> 6;
    const int lane = threadIdx.x & 63;
    const int row  = blockIdx.x * WAVES_PER_BLOCK + wave;   // b*L + l
    const int b    = row >> 9;                              // L = 512

    const float4* prow4 = (const float4*)(pooler + (size_t)row * Dc);
    nv_float4*    orow4 = (nv_float4*)(out + (size_t)row * Dc);
    const float4* W0_4  = (const float4*)W;
    const float4* W1_4  = (const float4*)(W + Dc);
    const float4* b_4   = (const float4*)bvec;
    const float4* g_4   = (const float4*)gamma;
    const float4* be_4  = (const float4*)beta;

    const int id = ids[b];
    const float e0 = emb_table[id * 2 + 0];
    const float e1 = emb_table[id * 2 + 1];

    float4 t0[3], t1[3];
    float s00 = 0.f, s01 = 0.f, s11 = 0.f, S0 = 0.f, S1 = 0.f;

#pragma unroll
    for (int j = 0; j < 3; ++j) {
        const int idx4 = lane + j * 64;   // coalesced across wave
        float4 p  = prow4[idx4];
        float4 w0 = W0_4[idx4];
        float4 w1 = W1_4[idx4];
        float4 bd = b_4[idx4];
        float4 x;
        x.x = fmaf(e0, w0.x, fmaf(e1, w1.x, bd.x));
        x.y = fmaf(e0, w0.y, fmaf(e1, w1.y, bd.y));
        x.z = fmaf(e0, w0.z, fmaf(e1, w1.z, bd.z));
        x.w = fmaf(e0, w0.w, fmaf(e1, w1.w, bd.w));
        t0[j] = p;
        t1[j] = x;
        s00 += p.x*p.x + p.y*p.y + p.z*p.z + p.w*p.w;
        s01 += p.x*x.x + p.y*x.y + p.z*x.z + p.w*x.w;
        s11 += x.x*x.x + x.y*x.y + x.z*x.z + x.w*x.w;
        S0  += p.x + p.y + p.z + p.w;
        S1  += x.x + x.y + x.z + x.w;
    }

    // Full-wave butterfly reduction: every lane ends with the total.
#pragma unroll
    for (int off = 32; off > 0; off >>= 1) {
        s00 += __shfl_xor(s00, off);
        s01 += __shfl_xor(s01, off);
        s11 += __shfl_xor(s11, off);
        S0  += __shfl_xor(S0,  off);
        S1  += __shfl_xor(S1,  off);
    }

    // Two 2-way softmaxes (max-subtracted: s00 ~ O(768), naive exp overflows).
    const float m0  = fmaxf(s00, s01);
    const float a00 = __expf(s00 - m0);
    const float a01 = __expf(s01 - m0);
    const float r0  = 1.f / (a00 + a01);
    const float m1  = fmaxf(s01, s11);
    const float a10 = __expf(s01 - m1);
    const float a11 = __expf(s11 - m1);
    const float r1  = 1.f / (a10 + a11);
    const float w0s = a00 * r0 + a10 * r1;   // weight on t0
    const float w1s = a01 * r0 + a11 * r1;   // weight on t1

    const float invD = 1.f / (float)Dc;
    const float mean = (w0s * S0 + w1s * S1) * invD;
    const float ex2  = (w0s*w0s*s00 + 2.f*w0s*w1s*s01 + w1s*w1s*s11) * invD;
    const float var  = ex2 - mean * mean;
    const float rstd = rsqrtf(var + LN_EPS);

#pragma unroll
    for (int j = 0; j < 3; ++j) {
        const int idx4 = lane + j * 64;
        float4 gm = g_4[idx4];
        float4 bt = be_4[idx4];
        nv_float4 o;
        o.x = (fmaf(w0s, t0[j].x, w1s * t1[j].x) - mean) * rstd * gm.x + bt.x;
        o.y = (fmaf(w0s, t0[j].y, w1s * t1[j].y) - mean) * rstd * gm.y + bt.y;
        o.z = (fmaf(w0s, t0[j].z, w1s * t1[j].z) - mean) * rstd * gm.z + bt.z;
        o.w = (fmaf(w0s, t0[j].w, w1s * t1[j].w) - mean) * rstd * gm.w + bt.w;
        __builtin_nontemporal_store(o, &orow4[idx4]);
    }
}

extern "C" void kernel_launch(void* const* d_in, const int* in_sizes, int n_in,
                              void* d_out, int out_size, void* d_ws, size_t ws_size,
                              hipStream_t stream) {
    const int*   ids       = (const int*)  d_in[0];
    const float* pooler    = (const float*)d_in[1];
    const float* emb_table = (const float*)d_in[2];
    const float* W_dense   = (const float*)d_in[3];
    const float* b_dense   = (const float*)d_in[4];
    const float* gamma     = (const float*)d_in[5];
    const float* beta      = (const float*)d_in[6];
    float* out = (float*)d_out;

    const int nrows = Bc * Lc;  // 32768
    hipLaunchKernelGGL(hier_attn_ln_kernel,
                       dim3(nrows / WAVES_PER_BLOCK), dim3(64 * WAVES_PER_BLOCK),
                       0, stream,
                       ids, pooler, emb_table, W_dense, b_dense, gamma, beta, out);
}